// Round 9
// baseline (2101.482 us; speedup 1.0000x reference)
//
#include <hip/hip_runtime.h>
#include <math.h>

#define NB  256
#define T   1024
#define DIN 64
#define H   128
#define G4  512

typedef __attribute__((ext_vector_type(8))) short    bf16x8;
typedef __attribute__((ext_vector_type(4))) float    f32x4;
typedef __attribute__((ext_vector_type(4))) _Float16 f16x4;
typedef __attribute__((ext_vector_type(8))) _Float16 f16x8;

#define DPPQ(v, CTRL) __int_as_float(__builtin_amdgcn_update_dpp(0, __float_as_int(v), (CTRL), 0xf, 0xf, true))

__device__ __forceinline__ float sigf(float x)   { return 1.0f / (1.0f + __expf(-x)); }
__device__ __forceinline__ float tanhf_(float x) { return 2.0f / (1.0f + __expf(-2.0f * x)) - 1.0f; }

__device__ __forceinline__ void split_bf16(float x, short& hi, short& lo) {
    unsigned u = __float_as_uint(x);
    unsigned hb = (u + 0x7fffu + ((u >> 16) & 1u)) >> 16;
    hi = (short)hb;
    float r = x - __uint_as_float(hb << 16);
    unsigned u2 = __float_as_uint(r);
    lo = (short)((u2 + 0x7fffu + ((u2 >> 16) & 1u)) >> 16);
}

struct SJ {                       // one scan job (one layer, one time tile)
    const float* xg;              // [NB*TILE][512] gate' order, no bias
    const float* whh;             // [512][128] original gate order
    const float* bias;            // [512] original order
    const float* h0;              // [NB][128] initial h for this layer
    float* sth; float* stc;       // [NB][128] carried state
    _Float16* hout;               // layer0: [NB*TILE][128] f16 (else null)
    int first;                    // t0 == 0 ?
    int dofc;                     // fuse final FC (layer1 last tile)
};

// ---------------------------------------------------------------------------
// Dual-job recurrent scan, MFMA matvec, TWO batch elements per block.
// Waves 0-3 -> batch 2*blk, waves 4-7 -> batch 2*blk+1. Each wave covers
// 128 gate' columns as EIGHT MFMA N-tiles (4 for hu 0..63 via gp0=tl,
// 4 for hu 64..127 via gp1=tl+256) -- full 512-gate coverage per batch
// (R8's bug: only 256 were computed). __launch_bounds__(512,2) gives the
// 256-VGPR budget so the 128-VGPR wfrag + 8 accs stay architectural.
// A = h broadcast over M rows; gate extraction = 3 cndmask per set; DPP
// quad exchange + fp32 nonlinearity for both hu0 and hu1; ONE barrier/step.
// ---------------------------------------------------------------------------
template<int TILE>
__global__ __launch_bounds__(512, 2)
void scan2(SJ ja, SJ jb, int nbA,
           const float* __restrict__ fcw, const float* __restrict__ fcb,
           float* __restrict__ out)
{
    __shared__ _Float16 __align__(16) lds_h[2][2][H];   // [buf][half][hu]
    __shared__ float lds_r[2][H];

    const int bid = blockIdx.x;
    const bool isA = bid < nbA;
    const SJ J = isA ? ja : jb;
    const int bl = isA ? bid : bid - nbA;

    const int t    = threadIdx.x;
    const int lane = t & 63;
    const int w    = t >> 6;       // 0..7
    const int wh   = w >> 2;       // batch half
    const int w4   = w & 3;        // wave within half
    const int b    = 2 * bl + wh;  // batch element

    const int tl   = 64 * w4 + lane;   // 0..255 within half
    const int typ  = tl & 3;
    const int hu0  = tl >> 2;          // 0..63
    const int hu1  = hu0 + 64;
    const int gp0  = tl;               // gate' index set 0
    const int gp1  = tl + 256;         // gate' index set 1
    const int kt_grp = lane >> 4;

    // B fragments: 8 N-tiles. j<4 -> gate' cols 64*w4+16j+(lane&15) (hu 0..63),
    // j>=4 -> 256 + 64*w4 + 16(j-4) + (lane&15) (hu 64..127).
    // k = 32*kt + kt_grp*8 + jj (16x16x32 f16 B-operand layout).
    f16x8 wfrag[8][4];
    #pragma unroll
    for (int j = 0; j < 8; ++j) {
        const int n  = ((j < 4) ? (64 * w4 + 16 * j) : (256 + 64 * w4 + 16 * (j - 4)))
                       + (lane & 15);
        const int pn = (n & 3) * 128 + (n >> 2);     // original gate row
        const float* wr = J.whh + (size_t)pn * H;
        #pragma unroll
        for (int kt = 0; kt < 4; ++kt) {
            const int base = 32 * kt + kt_grp * 8;
            float4 v0 = *(const float4*)(wr + base);
            float4 v1 = *(const float4*)(wr + base + 4);
            wfrag[j][kt] = (f16x8){(_Float16)v0.x, (_Float16)v0.y, (_Float16)v0.z, (_Float16)v0.w,
                                   (_Float16)v1.x, (_Float16)v1.y, (_Float16)v1.z, (_Float16)v1.w};
        }
    }
    const float bj0 = J.bias[typ * 128 + hu0];
    const float bj1 = J.bias[typ * 128 + hu1];

    if (w4 < 2) {
        int ii = 64 * w4 + lane;   // 0..127
        float hv = J.first ? J.h0[(size_t)b * H + ii] : J.sth[(size_t)b * H + ii];
        lds_h[0][wh][ii] = (_Float16)hv;
    }
    float c0 = J.first ? 0.0f : J.stc[(size_t)b * H + hu0];
    float c1 = J.first ? 0.0f : J.stc[(size_t)b * H + hu1];
    __syncthreads();

    const float* xgb = J.xg + (size_t)b * TILE * G4;
    float xA0 = xgb[gp0],      xB0 = xgb[gp1];
    float xA1 = (TILE > 1) ? xgb[G4 + gp0] : 0.0f;
    float xB1 = (TILE > 1) ? xgb[G4 + gp1] : 0.0f;

    const bool s4 = (lane & 16) != 0;
    const bool s5 = (lane & 32) != 0;

    float h0reg = 0.0f, h1reg = 0.0f;
    int cur = 0;

    for (int tt = 0; tt < TILE; ++tt) {
        // A fragments: h broadcast over M; af[kt][jj] = h[32kt + kt_grp*8 + jj]
        const _Float16* hb = &lds_h[cur][wh][0];
        f16x8 af[4];
        #pragma unroll
        for (int kt = 0; kt < 4; ++kt)
            af[kt] = *(const f16x8*)(hb + 32 * kt + kt_grp * 8);

        const f32x4 z = (f32x4){0.f, 0.f, 0.f, 0.f};
        f32x4 acc[8];
        #pragma unroll
        for (int j = 0; j < 8; ++j)
            acc[j] = __builtin_amdgcn_mfma_f32_16x16x32_f16(af[0], wfrag[j][0], z, 0, 0, 0);
        #pragma unroll
        for (int kt = 1; kt < 4; ++kt)
            #pragma unroll
            for (int j = 0; j < 8; ++j)
                acc[j] = __builtin_amdgcn_mfma_f32_16x16x32_f16(af[kt], wfrag[j][kt], acc[j], 0, 0, 0);

        // extraction: gate' col = (lane&15) of N-tile (lane>>4); rows identical
        float glo0 = s4 ? acc[1][0] : acc[0][0];
        float ghi0 = s4 ? acc[3][0] : acc[2][0];
        float g0   = (s5 ? ghi0 : glo0) + xA0 + bj0;
        float glo1 = s4 ? acc[5][0] : acc[4][0];
        float ghi1 = s4 ? acc[7][0] : acc[6][0];
        float g1   = (s5 ? ghi1 : glo1) + xB0 + bj1;

        xA0 = xA1; xB0 = xB1;
        int tn = (tt + 2 < TILE) ? (tt + 2) : (TILE - 1);
        xA1 = xgb[(size_t)tn * G4 + gp0];
        xB1 = xgb[(size_t)tn * G4 + gp1];

        // quad exchange + nonlinearity, set 0 (hu0)
        {
            float gi = DPPQ(g0, 0x00), gf = DPPQ(g0, 0x55);
            float gg = DPPQ(g0, 0xAA), go = DPPQ(g0, 0xFF);
            c0 = sigf(gf) * c0 + sigf(gi) * tanhf_(gg);
            h0reg = sigf(go) * tanhf_(c0);
        }
        // set 1 (hu1)
        {
            float gi = DPPQ(g1, 0x00), gf = DPPQ(g1, 0x55);
            float gg = DPPQ(g1, 0xAA), go = DPPQ(g1, 0xFF);
            c1 = sigf(gf) * c1 + sigf(gi) * tanhf_(gg);
            h1reg = sigf(go) * tanhf_(c1);
        }

        if (typ == 0) {
            lds_h[cur ^ 1][wh][hu0] = (_Float16)h0reg;
            lds_h[cur ^ 1][wh][hu1] = (_Float16)h1reg;
            if (J.hout) {
                J.hout[((size_t)b * TILE + tt) * H + hu0] = (_Float16)h0reg;
                J.hout[((size_t)b * TILE + tt) * H + hu1] = (_Float16)h1reg;
            }
        }
        cur ^= 1;
        __syncthreads();
    }

    if (typ == 0) {
        J.sth[(size_t)b * H + hu0] = h0reg;
        J.sth[(size_t)b * H + hu1] = h1reg;
        J.stc[(size_t)b * H + hu0] = c0;
        J.stc[(size_t)b * H + hu1] = c1;
    }

    if (J.dofc) {
        if (typ == 0) {
            lds_r[wh][hu0] = h0reg * fcw[hu0];
            lds_r[wh][hu1] = h1reg * fcw[hu1];
        }
        __syncthreads();
        if (lane == 0 && w4 == 0) {
            float s = fcb[0];
            for (int k = 0; k < H; ++k) s += lds_r[wh][k];
            out[b] = s;
        }
    }
}

// ---------------------------------------------------------------------------
// MFMA GEMM: Out[r][n'] = sum_k A[r][k] * W[perm(n')][k]; bf16 3-term split.
// A may be fp32 or f16 (aHalf). Dual-job launch; tile 128x128, BK=64.
// ---------------------------------------------------------------------------
__global__ __launch_bounds__(256, 2)
void gemm_xg(const void* __restrict__ A0, const float* __restrict__ W0,
             float* __restrict__ O0, int K0, int As0, int t00, int aH0,
             const void* __restrict__ A1, const float* __restrict__ W1,
             float* __restrict__ O1, int K1, int As1, int t01, int aH1,
             int nbA, int lgT, int lgM)
{
    __shared__ short Ah[128][72], Al[128][72], Wh[128][72], Wl[128][72];

    const void* A; const float* W; float* O; int K, Astride, t0, aHalf;
    int bid = blockIdx.x;
    if (bid < nbA) { A = A0; W = W0; O = O0; K = K0; Astride = As0; t0 = t00; aHalf = aH0; }
    else { bid -= nbA; A = A1; W = W1; O = O1; K = K1; Astride = As1; t0 = t01; aHalf = aH1; }

    const int Mmask = (1 << lgM) - 1;
    const int m0 = (bid & Mmask) << 7;
    const int n0 = (bid >> lgM) << 7;
    const int Tmask = (1 << lgT) - 1;

    const int j = threadIdx.x;
    const int lane = j & 63, wv = j >> 6;
    const int wm = wv >> 1, wn = wv & 1;
    const int q = lane >> 4, n16 = lane & 15;

    f32x4 acc[4][4];
    #pragma unroll
    for (int a = 0; a < 4; ++a)
        #pragma unroll
        for (int bq = 0; bq < 4; ++bq) acc[a][bq] = (f32x4){0.f, 0.f, 0.f, 0.f};

    const int npass = K >> 6;
    for (int kp = 0; kp < npass; ++kp) {
        #pragma unroll
        for (int it = 0; it < 8; ++it) {
            int cidx = j + it * 256;
            int r = cidx >> 4, kc = (cidx & 15) << 2;
            int gr = m0 + r;
            size_t arow = (size_t)(gr >> lgT) * Astride + t0 + (gr & Tmask);
            float4 v;
            if (aHalf) {
                f16x4 hv4 = *(const f16x4*)((const _Float16*)A + arow * K + kp * 64 + kc);
                v = make_float4((float)hv4[0], (float)hv4[1], (float)hv4[2], (float)hv4[3]);
            } else {
                v = *(const float4*)((const float*)A + arow * K + kp * 64 + kc);
            }
            short h0s, l0s, h1s, l1s, h2s, l2s, h3s, l3s;
            split_bf16(v.x, h0s, l0s); split_bf16(v.y, h1s, l1s);
            split_bf16(v.z, h2s, l2s); split_bf16(v.w, h3s, l3s);
            *(short4*)&Ah[r][kc] = make_short4(h0s, h1s, h2s, h3s);
            *(short4*)&Al[r][kc] = make_short4(l0s, l1s, l2s, l3s);
        }
        #pragma unroll
        for (int it = 0; it < 8; ++it) {
            int cidx = j + it * 256;
            int r = cidx >> 4, kc = (cidx & 15) << 2;
            int n = n0 + r;
            int pn = (n & 3) * 128 + (n >> 2);
            float4 v = *(const float4*)(W + (size_t)pn * K + kp * 64 + kc);
            short h0s, l0s, h1s, l1s, h2s, l2s, h3s, l3s;
            split_bf16(v.x, h0s, l0s); split_bf16(v.y, h1s, l1s);
            split_bf16(v.z, h2s, l2s); split_bf16(v.w, h3s, l3s);
            *(short4*)&Wh[r][kc] = make_short4(h0s, h1s, h2s, h3s);
            *(short4*)&Wl[r][kc] = make_short4(l0s, l1s, l2s, l3s);
        }
        __syncthreads();

        #pragma unroll
        for (int kt = 0; kt < 2; ++kt) {
            const int kk = kt * 32 + q * 8;
            bf16x8 ah[4], al[4];
            #pragma unroll
            for (int mt = 0; mt < 4; ++mt) {
                int row = wm * 64 + mt * 16 + n16;
                ah[mt] = *(const bf16x8*)&Ah[row][kk];
                al[mt] = *(const bf16x8*)&Al[row][kk];
            }
            #pragma unroll
            for (int nt = 0; nt < 4; ++nt) {
                int col = wn * 64 + nt * 16 + n16;
                bf16x8 bh = *(const bf16x8*)&Wh[col][kk];
                bf16x8 bl = *(const bf16x8*)&Wl[col][kk];
                #pragma unroll
                for (int mt = 0; mt < 4; ++mt) {
                    acc[mt][nt] = __builtin_amdgcn_mfma_f32_16x16x32_bf16(ah[mt], bh, acc[mt][nt], 0, 0, 0);
                    acc[mt][nt] = __builtin_amdgcn_mfma_f32_16x16x32_bf16(al[mt], bh, acc[mt][nt], 0, 0, 0);
                    acc[mt][nt] = __builtin_amdgcn_mfma_f32_16x16x32_bf16(ah[mt], bl, acc[mt][nt], 0, 0, 0);
                }
            }
        }
        __syncthreads();
    }

    #pragma unroll
    for (int mt = 0; mt < 4; ++mt) {
        #pragma unroll
        for (int nt = 0; nt < 4; ++nt) {
            int row = m0 + wm * 64 + mt * 16 + q * 4;
            int col = n0 + wn * 64 + nt * 16 + n16;
            #pragma unroll
            for (int r = 0; r < 4; ++r)
                O[(size_t)(row + r) * G4 + col] = acc[mt][nt][r];
        }
    }
}

template<int TILE>
static void run_all(const float* x, const float* h0,
                    const float* wih0, const float* whh0, const float* b0,
                    const float* wih1, const float* whh1, const float* b1,
                    const float* fcw, const float* fcb, float* out,
                    void* d_ws, hipStream_t stream)
{
    const int n_t = T / TILE;
    const int lgT = __builtin_ctz(TILE);
    const int lgM = lgT + 1;
    const int nbJ = 8 * TILE;   // (NB*TILE/128) * (512/128)
    const int nbS = NB / 2;     // scan blocks per job (2 batches/block)

    float*    xg0 = (float*)d_ws;
    float*    xg1 = xg0 + (size_t)NB * TILE * G4;
    _Float16* h0s = (_Float16*)(xg1 + (size_t)NB * TILE * G4);
    float*    st  = (float*)(h0s + (size_t)NB * TILE * H);
    float* st_h0 = st, *st_c0 = st + NB * H, *st_h1 = st + 2 * NB * H, *st_c1 = st + 3 * NB * H;

    SJ l0, l1;
    l0.whh = whh0; l0.bias = b0; l0.h0 = h0;               l0.sth = st_h0; l0.stc = st_c0;
    l0.xg = xg0;   l0.hout = h0s; l0.dofc = 0;
    l1.whh = whh1; l1.bias = b1; l1.h0 = h0 + (size_t)NB * H; l1.sth = st_h1; l1.stc = st_c1;
    l1.xg = xg1;   l1.hout = nullptr;

    // xg0(0)
    gemm_xg<<<nbJ, 256, 0, stream>>>(x, wih0, xg0, DIN, T, 0, 0,
                                     x, wih0, xg0, DIN, T, 0, 0, nbJ, lgT, lgM);
    // scan_l0 tile 0 (solo)
    l0.first = 1;
    scan2<TILE><<<nbS, 512, 0, stream>>>(l0, l0, nbS, fcw, fcb, out);

    for (int k = 0; k < n_t; ++k) {
        // gemm: xg1(k) from h0s (f16); plus xg0(k+1) from x if it exists
        if (k + 1 < n_t) {
            gemm_xg<<<2 * nbJ, 256, 0, stream>>>(
                h0s, wih1, xg1, H, TILE, 0, 1,
                x, wih0, xg0, DIN, T, (k + 1) * TILE, 0, nbJ, lgT, lgM);
            // combined: scan_l0(k+1) || scan_l1(k)
            l0.first = 0;
            l1.first = (k == 0);
            l1.dofc = 0;
            scan2<TILE><<<2 * nbS, 512, 0, stream>>>(l0, l1, nbS, fcw, fcb, out);
        } else {
            gemm_xg<<<nbJ, 256, 0, stream>>>(
                h0s, wih1, xg1, H, TILE, 0, 1,
                h0s, wih1, xg1, H, TILE, 0, 1, nbJ, lgT, lgM);
            // final scan_l1 (solo, fused FC)
            l1.first = (k == 0);
            l1.dofc = 1;
            scan2<TILE><<<nbS, 512, 0, stream>>>(l1, l1, nbS, fcw, fcb, out);
        }
    }
}

extern "C" void kernel_launch(void* const* d_in, const int* in_sizes, int n_in,
                              void* d_out, int out_size, void* d_ws, size_t ws_size,
                              hipStream_t stream)
{
    const float* x    = (const float*)d_in[0];
    const float* h0   = (const float*)d_in[1];
    const float* wih0 = (const float*)d_in[2];
    const float* whh0 = (const float*)d_in[3];
    const float* b0   = (const float*)d_in[4];
    const float* wih1 = (const float*)d_in[5];
    const float* whh1 = (const float*)d_in[6];
    const float* b1   = (const float*)d_in[7];
    const float* fcw  = (const float*)d_in[8];
    const float* fcb  = (const float*)d_in[9];
    float* out = (float*)d_out;

    int TILE = 256;
    while (TILE > 16) {
        size_t need = (size_t)NB * TILE * (2 * G4 * 4 + H * 2) + (size_t)4 * NB * H * 4;
        if (need <= ws_size) break;
        TILE >>= 1;
    }

    switch (TILE) {
        case 256: run_all<256>(x, h0, wih0, whh0, b0, wih1, whh1, b1, fcw, fcb, out, d_ws, stream); break;
        case 128: run_all<128>(x, h0, wih0, whh0, b0, wih1, whh1, b1, fcw, fcb, out, d_ws, stream); break;
        case  64: run_all< 64>(x, h0, wih0, whh0, b0, wih1, whh1, b1, fcw, fcb, out, d_ws, stream); break;
        default:  run_all< 32>(x, h0, wih0, whh0, b0, wih1, whh1, b1, fcw, fcb, out, d_ws, stream); break;
    }
}